// Round 10
// baseline (242.748 us; speedup 1.0000x reference)
//
#include <hip/hip_runtime.h>
#include <math.h>

#define BB 8
#define TT 100
#define PP 1000
#define NJ 52      // V regs per thread in k4 (50 real j, 2 pad)
#define GROW 56    // G row stride floats (224B, 16B aligned)

// ws layout (floats):
//   xk : [800][256] at 0        (204800)
//   XcT: [56][1000] at 204800   (56000)
//   G  : [800][56]  at 260800   (44800)

// Raw workgroup barrier: lgkmcnt(0) + s_barrier, NO vmcnt drain (keeps the xk
// register pipeline in flight; round-9 showed this is neutral vs __syncthreads,
// but it is free and strictly safer for the prefetch).
#define WAVE_BARRIER() asm volatile("s_waitcnt lgkmcnt(0)\ns_barrier" ::: "memory")

// ---------------- K1: xk[bt][j] = bias[j] + sum_k xt[bt][k]*kern[k][j] -----------------
__global__ __launch_bounds__(256) void k1_xk(const int* __restrict__ pro_id,
    const int* __restrict__ label, const float* __restrict__ X,
    const float* __restrict__ onehot, const float* __restrict__ kern,
    const float* __restrict__ bias, float* __restrict__ xk)
{
    __shared__ __align__(16) float xt[2][256];
    const int j = threadIdx.x;
    const int r0 = blockIdx.x * 2;
#pragma unroll
    for (int r = 0; r < 2; ++r) {
        int pid = pro_id[r0 + r];
        int lab = label[r0 + r];
        xt[r][j] = X[pid * 128 + (j & 127)] * onehot[lab * 256 + j];
    }
    __syncthreads();
    float acc0 = bias[j], acc1 = acc0;
    float kc[8];
#pragma unroll
    for (int i = 0; i < 8; ++i) kc[i] = kern[i * 256 + j];
    for (int kg = 0; kg < 32; ++kg) {
        float kn[8];
        const int kgn = (kg < 31) ? kg + 1 : 31;
#pragma unroll
        for (int i = 0; i < 8; ++i) kn[i] = kern[(kgn * 8 + i) * 256 + j];
        const int k0 = kg * 8;
        float4 xa0 = *(const float4*)&xt[0][k0];
        float4 xa1 = *(const float4*)&xt[0][k0 + 4];
        float4 xb0 = *(const float4*)&xt[1][k0];
        float4 xb1 = *(const float4*)&xt[1][k0 + 4];
        acc0 += xa0.x * kc[0] + xa0.y * kc[1] + xa0.z * kc[2] + xa0.w * kc[3]
              + xa1.x * kc[4] + xa1.y * kc[5] + xa1.z * kc[6] + xa1.w * kc[7];
        acc1 += xb0.x * kc[0] + xb0.y * kc[1] + xb0.z * kc[2] + xb0.w * kc[3]
              + xb1.x * kc[4] + xb1.y * kc[5] + xb1.z * kc[6] + xb1.w * kc[7];
#pragma unroll
        for (int i = 0; i < 8; ++i) kc[i] = kn[i];
    }
    xk[(r0 + 0) * 256 + j] = acc0;
    xk[(r0 + 1) * 256 + j] = acc1;
}

// ---------------- MID: blocks 0..3 = LSTM (2 batches each), 4..19 = XcT (k3) -----------
// LSTM v6: TWO independent batches per block, interleaved in one instruction
// stream. Rounds 3/6/9 proved the step cost is serial latency (ds_read ~120 +
// FMA chain + exp + bpermute ~120 + ds_write + barrier) with 1 wave/SIMD and
// nothing to hide it; prefetch/barrier tweaks were neutral. Batch B's chain
// issues while batch A's waits -> ILP 2 on a latency-bound loop. rcol VGPRs
// are SHARED (same weights). t=0 peeled (h(-1)=0 -> z=xk), so h rows = 100.
__global__ __launch_bounds__(256, 1) void mid(const float* __restrict__ xk,
    const float* __restrict__ rec, const float* __restrict__ W1,
    const float* __restrict__ X, const float* __restrict__ b1,
    float* __restrict__ G, float* __restrict__ XcT)
{
    __shared__ __align__(16) float smem[16128];  // 64512 B (<= 64 KB static limit)
    const int tid = threadIdx.x;

    if (blockIdx.x < 4) {
        float* hA  = smem;                // [100][64] = 25600 B
        float* hB  = smem + 6400;         // [100][64] = 25600 B
        float* w1s = smem + 12800;        // [64][52]  = 13312 B
        const int b = blockIdx.x;         // batches b and b+4
        const int l = tid & 63;
        const int w = tid >> 6;
        const int u = (w << 4) | (l & 15);
        const int g = l >> 4;
        const int col = (g << 6) | u;
        const int base = l & 15;

        for (int idx = tid; idx < 3200; idx += 256) {
            int u2 = idx / 50, jj = idx - u2 * 50;
            w1s[u2 * 52 + jj] = W1[idx];
        }
        float rcol[64];
#pragma unroll
        for (int u2 = 0; u2 < 64; ++u2) rcol[u2] = rec[u2 * 256 + col];

        const float* xkA = xk + b * TT * 256;
        const float* xkB = xk + (b + 4) * TT * 256;
        // depth-3 register pipelines, both batches
        float zA0 = xkA[col], zA1 = xkA[256 + col], zA2 = xkA[512 + col];
        float zB0 = xkB[col], zB1 = xkB[256 + col], zB2 = xkB[512 + col];
        float cA = 0.f, cB = 0.f;

        // ---- t = 0: h(-1)=0 -> z = xk, no matvec ----
        {
            float zA = zA0, zB = zB0;
            zA0 = zA1; zA1 = zA2; zA2 = xkA[3 * 256 + col];
            zB0 = zB1; zB1 = zB2; zB2 = xkB[3 * 256 + col];
            float actA, actB;
            if (g == 2) { actA = 2.f / (1.f + __expf(-2.f * zA)) - 1.f;
                          actB = 2.f / (1.f + __expf(-2.f * zB)) - 1.f; }
            else        { actA = 1.f / (1.f + __expf(-zA));
                          actB = 1.f / (1.f + __expf(-zB)); }
            float giA = __shfl(actA, base),      giB = __shfl(actB, base);
            float gfA = __shfl(actA, base + 16), gfB = __shfl(actB, base + 16);
            float ggA = __shfl(actA, base + 32), ggB = __shfl(actB, base + 32);
            float goA = __shfl(actA, base + 48), goB = __shfl(actB, base + 48);
            cA = gfA * cA + giA * ggA;
            cB = gfB * cB + giB * ggB;
            float hAv = goA * (2.f / (1.f + __expf(-2.f * cA)) - 1.f);
            float hBv = goB * (2.f / (1.f + __expf(-2.f * cB)) - 1.f);
            if (g == 0) { hA[u] = hAv; hB[u] = hBv; }
            WAVE_BARRIER();
        }

        for (int t = 1; t < TT; ++t) {
            float aA0 = zA0, aA1 = 0.f, aA2 = 0.f, aA3 = 0.f;
            float aB0 = zB0, aB1 = 0.f, aB2 = 0.f, aB3 = 0.f;
            zA0 = zA1; zA1 = zA2;
            zB0 = zB1; zB1 = zB2;
            int tn = (t + 3 < TT) ? t + 3 : TT - 1;
            zA2 = xkA[tn * 256 + col];        // in flight ~3 steps (no vmcnt drain)
            zB2 = xkB[tn * 256 + col];
            const float4* hApt = (const float4*)&hA[(t - 1) * 64];
            const float4* hBpt = (const float4*)&hB[(t - 1) * 64];
#pragma unroll
            for (int m = 0; m < 16; ++m) {
                float4 ha = hApt[m];          // broadcast ds_read_b128
                float4 hb = hBpt[m];          // independent chain B hides A's wait
                aA0 += ha.x * rcol[4 * m + 0]; aB0 += hb.x * rcol[4 * m + 0];
                aA1 += ha.y * rcol[4 * m + 1]; aB1 += hb.y * rcol[4 * m + 1];
                aA2 += ha.z * rcol[4 * m + 2]; aB2 += hb.z * rcol[4 * m + 2];
                aA3 += ha.w * rcol[4 * m + 3]; aB3 += hb.w * rcol[4 * m + 3];
            }
            float zA = (aA0 + aA1) + (aA2 + aA3);
            float zB = (aB0 + aB1) + (aB2 + aB3);
            float actA, actB;
            if (g == 2) { actA = 2.f / (1.f + __expf(-2.f * zA)) - 1.f;
                          actB = 2.f / (1.f + __expf(-2.f * zB)) - 1.f; }
            else        { actA = 1.f / (1.f + __expf(-zA));
                          actB = 1.f / (1.f + __expf(-zB)); }
            float giA = __shfl(actA, base),      giB = __shfl(actB, base);
            float gfA = __shfl(actA, base + 16), gfB = __shfl(actB, base + 16);
            float ggA = __shfl(actA, base + 32), ggB = __shfl(actB, base + 32);
            float goA = __shfl(actA, base + 48), goB = __shfl(actB, base + 48);
            cA = gfA * cA + giA * ggA;
            cB = gfB * cB + giB * ggB;
            float hAv = goA * (2.f / (1.f + __expf(-2.f * cA)) - 1.f);
            float hBv = goB * (2.f / (1.f + __expf(-2.f * cB)) - 1.f);
            if (g == 0) { hA[t * 64 + u] = hAv; hB[t * 64 + u] = hBv; }
            WAVE_BARRIER();
        }
        __syncthreads();   // full fence before the tail

        // ---- G tail (all 256 threads), both batches ----
#pragma unroll
        for (int bb2 = 0; bb2 < 2; ++bb2) {
            const float* hbuf = bb2 ? hB : hA;
            const int brow0 = (b + 4 * bb2) * TT;
            for (int idx = tid; idx < TT * 13; idx += 256) {
                int row = idx / 13;
                int m = idx - row * 13;
                int j = 4 * m;
                const float* hrow = &hbuf[row * 64];
                float ax = 0.f, ay = 0.f, az = 0.f, aw = 0.f;
#pragma unroll
                for (int u4 = 0; u4 < 16; ++u4) {
                    float4 hv  = *(const float4*)&hrow[4 * u4];
                    float4 w0  = *(const float4*)&w1s[(4 * u4 + 0) * 52 + j];
                    float4 w1v = *(const float4*)&w1s[(4 * u4 + 1) * 52 + j];
                    float4 w2  = *(const float4*)&w1s[(4 * u4 + 2) * 52 + j];
                    float4 w3  = *(const float4*)&w1s[(4 * u4 + 3) * 52 + j];
                    ax += hv.x * w0.x + hv.y * w1v.x + hv.z * w2.x + hv.w * w3.x;
                    ay += hv.x * w0.y + hv.y * w1v.y + hv.z * w2.y + hv.w * w3.y;
                    az += hv.x * w0.z + hv.y * w1v.z + hv.z * w2.z + hv.w * w3.z;
                    aw += hv.x * w0.w + hv.y * w1v.w + hv.z * w2.w + hv.w * w3.w;
                }
                if (m == 12) { az = 0.f; aw = 0.f; }   // cols 50,51 = 0
                *(float4*)&G[(brow0 + row) * GROW + j] = make_float4(ax, ay, az, aw);
            }
        }
    } else {
        // ---- k3: XcT[j][p] = b1[j] + sum_k X[p][k]*W1[64+k][j] ----
        float* Xs  = smem;          // [128][65]
        float* W1T = smem + 8320;   // [50][128]
        const int p0 = (blockIdx.x - 4) * 64;
        for (int idx = tid; idx < 6400; idx += 256) {
            int k = idx & 127, jj = idx >> 7;
            W1T[jj * 128 + k] = W1[(64 + k) * 50 + jj];
        }
#pragma unroll
        for (int r = 0; r < 8; ++r) {
            int flat = (tid + 256 * r) * 4;
            int i = flat >> 7;
            int k = flat & 127;
            int p = p0 + i;
            float4 v = make_float4(0.f, 0.f, 0.f, 0.f);
            if (p < PP) v = *(const float4*)&X[p * 128 + k];
            Xs[(k + 0) * 65 + i] = v.x;
            Xs[(k + 1) * 65 + i] = v.y;
            Xs[(k + 2) * 65 + i] = v.z;
            Xs[(k + 3) * 65 + i] = v.w;
        }
        __syncthreads();
        const int ploc = tid & 63;
        const int j0 = tid >> 6;
        float acc[13];
#pragma unroll
        for (int m = 0; m < 13; ++m) {
            int jj = j0 * 13 + m;
            acc[m] = (jj < 50) ? b1[jj] : 0.f;
        }
        for (int k4 = 0; k4 < 32; ++k4) {
            const int k = 4 * k4;
            float x0 = Xs[(k + 0) * 65 + ploc];
            float x1 = Xs[(k + 1) * 65 + ploc];
            float x2 = Xs[(k + 2) * 65 + ploc];
            float x3 = Xs[(k + 3) * 65 + ploc];
#pragma unroll
            for (int m = 0; m < 13; ++m) {
                int jj = j0 * 13 + m;
                if (jj < 50) {
                    float4 wv = *(const float4*)&W1T[jj * 128 + k];
                    acc[m] += x0 * wv.x + x1 * wv.y + x2 * wv.z + x3 * wv.w;
                }
            }
        }
        int p = p0 + ploc;
        if (p < PP) {
#pragma unroll
            for (int m = 0; m < 13; ++m) {
                int jj = j0 * 13 + m;
                if (jj < 50) XcT[jj * PP + p] = acc[m];
            }
        }
        for (int idx = tid; idx < 6 * 64; idx += 256) {
            int r = 50 + (idx >> 6);
            int pp = p0 + (idx & 63);
            if (pp < PP) XcT[r * PP + pp] = 0.f;
        }
    }
}

// ---------------- K4: suffix-accumulate V[p,j] += a[s,p]*Gs[s,j]; emit per t-chunk -----
__global__ __launch_bounds__(256) void k4_main(const int* __restrict__ pro_id,
    const float* __restrict__ cos_X, const float* __restrict__ XcT,
    const float* __restrict__ G, const float* __restrict__ W2,
    const float* __restrict__ b2, float* __restrict__ out)
{
    __shared__ __align__(16) float Gs[TT * GROW];  // 22.4 KB
    __shared__ float w2s[NJ];
    __shared__ int spid[TT];
    const int b = blockIdx.z;
    const int p = blockIdx.y * 256 + threadIdx.x;
    const int ci = blockIdx.x;
    const int t0 = ci * 7;
    const int t1 = (t0 + 7 < TT) ? (t0 + 7) : TT;
    const bool valid = p < PP;
    const int pc = valid ? p : 0;
    const int tid = threadIdx.x;

    {
        const float4* Gg = (const float4*)(G + b * TT * GROW);
        float4* Gd = (float4*)Gs;
        for (int idx = tid; idx < TT * GROW / 4; idx += 256) Gd[idx] = Gg[idx];
        if (tid < TT) spid[tid] = pro_id[b * TT + tid];
        if (tid < NJ) w2s[tid] = (tid < 50) ? W2[tid] : 0.f;
    }

    float V[NJ];
#pragma unroll
    for (int jj = 0; jj < NJ; ++jj) V[jj] = XcT[jj * PP + pc];
    const float b2v = b2[0];
    __syncthreads();

    const float* cb = cos_X + pc;
    float a0 = cb[spid[99] * PP];
    float a1 = cb[spid[98] * PP];
    float a2 = cb[spid[97] * PP];
    float a3 = cb[spid[96] * PP];

    for (int s = TT - 1; s >= t0; --s) {
        float a = a0; a0 = a1; a1 = a2; a2 = a3;
        int sp = s - 4;
        if (sp < t0) sp = t0;
        a3 = cb[spid[sp] * PP];
        const float4* G4 = (const float4*)&Gs[s * GROW];
#pragma unroll
        for (int jv = 0; jv < 13; ++jv) {
            float4 gv = G4[jv];
            V[4 * jv + 0] += a * gv.x;
            V[4 * jv + 1] += a * gv.y;
            V[4 * jv + 2] += a * gv.z;
            V[4 * jv + 3] += a * gv.w;
        }
        if (s < t1) {
            float acc = b2v;
#pragma unroll
            for (int jv = 0; jv < 13; ++jv) {
                float4 wv = *(const float4*)&w2s[4 * jv];
                acc += wv.x * fmaxf(V[4 * jv + 0], 0.f)
                     + wv.y * fmaxf(V[4 * jv + 1], 0.f)
                     + wv.z * fmaxf(V[4 * jv + 2], 0.f)
                     + wv.w * fmaxf(V[4 * jv + 3], 0.f);
            }
            if (valid) out[(b * TT + s) * PP + p] = acc;
        }
    }
}

extern "C" void kernel_launch(void* const* d_in, const int* in_sizes, int n_in,
                              void* d_out, int out_size, void* d_ws, size_t ws_size,
                              hipStream_t stream)
{
    const int* pro_id  = (const int*)d_in[0];
    const int* label   = (const int*)d_in[1];
    const float* X     = (const float*)d_in[3];
    const float* cos_X = (const float*)d_in[4];
    // d_in[5] trimatrix: structurally tril(ones) — suffix-sum semantics hardcoded
    const float* onehot = (const float*)d_in[6];
    const float* lk    = (const float*)d_in[7];
    const float* lr    = (const float*)d_in[8];
    const float* lb    = (const float*)d_in[9];
    const float* W1    = (const float*)d_in[10];
    const float* b1    = (const float*)d_in[11];
    const float* W2    = (const float*)d_in[12];
    const float* b2    = (const float*)d_in[13];

    float* ws  = (float*)d_ws;
    float* xk  = ws;            // 204800
    float* XcT = ws + 204800;   // 56000
    float* G   = ws + 260800;   // 44800
    float* out = (float*)d_out;

    hipLaunchKernelGGL(k1_xk,  dim3(400),      dim3(256), 0, stream,
                       pro_id, label, X, onehot, lk, lb, xk);
    hipLaunchKernelGGL(mid,    dim3(20),       dim3(256), 0, stream,
                       xk, lr, W1, X, b1, G, XcT);
    hipLaunchKernelGGL(k4_main,dim3(15, 4, 8), dim3(256), 0, stream,
                       pro_id, cos_X, XcT, G, W2, b2, out);
}

// Round 11
// 198.485 us; speedup vs baseline: 1.2230x; 1.2230x over previous
//
#include <hip/hip_runtime.h>
#include <math.h>

#define BB 8
#define TT 100
#define PP 1000
#define NJ 52      // V regs per thread in k4 (50 real j, 2 pad)
#define GROW 56    // G row stride floats (224B, 16B aligned)

typedef _Float16 half2v __attribute__((ext_vector_type(2)));

__device__ __forceinline__ half2v as_h2(float f) {
    union { float x; half2v h; } u; u.x = f; return u.h;
}

// ws layout (floats):
//   xk : [800][256] at 0        (204800)
//   XcT: [56][1000] at 204800   (56000)
//   G  : [800][56]  at 260800   (44800)

// ---------------- K1: xk[bt][j] = bias[j] + sum_k xt[bt][k]*kern[k][j] -----------------
__global__ __launch_bounds__(256) void k1_xk(const int* __restrict__ pro_id,
    const int* __restrict__ label, const float* __restrict__ X,
    const float* __restrict__ onehot, const float* __restrict__ kern,
    const float* __restrict__ bias, float* __restrict__ xk)
{
    __shared__ __align__(16) float xt[2][256];
    const int j = threadIdx.x;
    const int r0 = blockIdx.x * 2;
#pragma unroll
    for (int r = 0; r < 2; ++r) {
        int pid = pro_id[r0 + r];
        int lab = label[r0 + r];
        xt[r][j] = X[pid * 128 + (j & 127)] * onehot[lab * 256 + j];
    }
    __syncthreads();
    float acc0 = bias[j], acc1 = acc0;
    float kc[8];
#pragma unroll
    for (int i = 0; i < 8; ++i) kc[i] = kern[i * 256 + j];
    for (int kg = 0; kg < 32; ++kg) {
        float kn[8];
        const int kgn = (kg < 31) ? kg + 1 : 31;
#pragma unroll
        for (int i = 0; i < 8; ++i) kn[i] = kern[(kgn * 8 + i) * 256 + j];
        const int k0 = kg * 8;
        float4 xa0 = *(const float4*)&xt[0][k0];
        float4 xa1 = *(const float4*)&xt[0][k0 + 4];
        float4 xb0 = *(const float4*)&xt[1][k0];
        float4 xb1 = *(const float4*)&xt[1][k0 + 4];
        acc0 += xa0.x * kc[0] + xa0.y * kc[1] + xa0.z * kc[2] + xa0.w * kc[3]
              + xa1.x * kc[4] + xa1.y * kc[5] + xa1.z * kc[6] + xa1.w * kc[7];
        acc1 += xb0.x * kc[0] + xb0.y * kc[1] + xb0.z * kc[2] + xb0.w * kc[3]
              + xb1.x * kc[4] + xb1.y * kc[5] + xb1.z * kc[6] + xb1.w * kc[7];
#pragma unroll
        for (int i = 0; i < 8; ++i) kc[i] = kn[i];
    }
    xk[(r0 + 0) * 256 + j] = acc0;
    xk[(r0 + 1) * 256 + j] = acc1;
}

// ---------------- MID: blocks 0..7 = LSTM (1 batch), blocks 8..23 = XcT (k3) -----------
// LSTM v7: SINGLE WAVE per batch, lane u owns unit u AND all 4 of its gates
// (cols u,64+u,128+u,192+u) -> c/h updates are lane-local: NO shfl, NO barrier,
// NO cross-wave exchange in the recurrence (R3/6/9: ~1600cyc/step from those;
// R10: doubling per-step work made it worse). rec held as v_dot2_f32_f16 pairs:
// 4x32 half2 = 128 VGPRs (fits; R7's f32 needed 256+ and spilled). h broadcast
// via one 128B f16 LDS row, 8 ds_read_b128, wave-synchronous.
__global__ __launch_bounds__(256, 1) void mid(const float* __restrict__ xk,
    const float* __restrict__ rec, const float* __restrict__ W1,
    const float* __restrict__ X, const float* __restrict__ b1,
    float* __restrict__ G, float* __restrict__ XcT)
{
    __shared__ __align__(16) float smem[14720];  // 58.9 KB union
    const int tid = threadIdx.x;

    if (blockIdx.x < 8) {
        float* h_all  = smem;            // [100][64] f32 = 25600 B (for G tail)
        float* hwork  = smem + 6400;     // [64] f16 = 128 B (pad to 32 floats)
        float* w1s    = smem + 6432;     // [64][52] = 13312 B
        const int b = blockIdx.x;

        // waves 1..3 stage w1s while wave 0 sets up the recurrence
        if (tid >= 64) {
            for (int idx = tid - 64; idx < 3200; idx += 192) {
                int u2 = idx / 50, jj = idx - u2 * 50;
                w1s[u2 * 52 + jj] = W1[idx];
            }
        }

        if (tid < 64) {                  // wave 0: the whole recurrence
            const int u = tid;
            // rec as f16 dot2 pairs: rp[g][m] = (rec[2m][g*64+u], rec[2m+1][g*64+u])
            half2v rp[4][32];
#pragma unroll
            for (int m = 0; m < 32; ++m) {
#pragma unroll
                for (int g2 = 0; g2 < 4; ++g2) {
                    float r0 = rec[(2 * m) * 256 + g2 * 64 + u];
                    float r1 = rec[(2 * m + 1) * 256 + g2 * 64 + u];
                    half2v pv; pv.x = (_Float16)r0; pv.y = (_Float16)r1;
                    rp[g2][m] = pv;
                }
            }
            // h(-1) = 0
            ((_Float16*)hwork)[u] = (_Float16)0.f;

            const float* xkb = xk + b * TT * 256;
            // depth-3 xk pipeline, 4 gate columns each
            float xi0 = xkb[u],           xf0 = xkb[64 + u],
                  xg0 = xkb[128 + u],     xo0 = xkb[192 + u];
            float xi1 = xkb[256 + u],     xf1 = xkb[256 + 64 + u],
                  xg1 = xkb[256 + 128 + u], xo1 = xkb[256 + 192 + u];
            float xi2 = xkb[512 + u],     xf2 = xkb[512 + 64 + u],
                  xg2 = xkb[512 + 128 + u], xo2 = xkb[512 + 192 + u];
            float c = 0.f;

            for (int t = 0; t < TT; ++t) {
                float zi = xi0, zf = xf0, zg = xg0, zo = xo0;
                xi0 = xi1; xf0 = xf1; xg0 = xg1; xo0 = xo1;
                xi1 = xi2; xf1 = xf2; xg1 = xg2; xo1 = xo2;
                int tn = (t + 3 < TT) ? t + 3 : TT - 1;
                const float* xp = xkb + tn * 256;
                xi2 = xp[u]; xf2 = xp[64 + u]; xg2 = xp[128 + u]; xo2 = xp[192 + u];

                const float4* hw4 = (const float4*)hwork;
#pragma unroll
                for (int ch = 0; ch < 8; ++ch) {
                    float4 hv = hw4[ch];          // broadcast, 4 h2 pairs
                    half2v p0 = as_h2(hv.x), p1 = as_h2(hv.y),
                           p2 = as_h2(hv.z), p3 = as_h2(hv.w);
                    zi = __builtin_amdgcn_fdot2(p0, rp[0][ch * 4 + 0], zi, false);
                    zf = __builtin_amdgcn_fdot2(p0, rp[1][ch * 4 + 0], zf, false);
                    zg = __builtin_amdgcn_fdot2(p0, rp[2][ch * 4 + 0], zg, false);
                    zo = __builtin_amdgcn_fdot2(p0, rp[3][ch * 4 + 0], zo, false);
                    zi = __builtin_amdgcn_fdot2(p1, rp[0][ch * 4 + 1], zi, false);
                    zf = __builtin_amdgcn_fdot2(p1, rp[1][ch * 4 + 1], zf, false);
                    zg = __builtin_amdgcn_fdot2(p1, rp[2][ch * 4 + 1], zg, false);
                    zo = __builtin_amdgcn_fdot2(p1, rp[3][ch * 4 + 1], zo, false);
                    zi = __builtin_amdgcn_fdot2(p2, rp[0][ch * 4 + 2], zi, false);
                    zf = __builtin_amdgcn_fdot2(p2, rp[1][ch * 4 + 2], zf, false);
                    zg = __builtin_amdgcn_fdot2(p2, rp[2][ch * 4 + 2], zg, false);
                    zo = __builtin_amdgcn_fdot2(p2, rp[3][ch * 4 + 2], zo, false);
                    zi = __builtin_amdgcn_fdot2(p3, rp[0][ch * 4 + 3], zi, false);
                    zf = __builtin_amdgcn_fdot2(p3, rp[1][ch * 4 + 3], zf, false);
                    zg = __builtin_amdgcn_fdot2(p3, rp[2][ch * 4 + 3], zg, false);
                    zo = __builtin_amdgcn_fdot2(p3, rp[3][ch * 4 + 3], zo, false);
                }
                float gi = 1.f / (1.f + __expf(-zi));
                float gf = 1.f / (1.f + __expf(-zf));
                float gg = 2.f / (1.f + __expf(-2.f * zg)) - 1.f;
                float go = 1.f / (1.f + __expf(-zo));
                c = gf * c + gi * gg;
                float h = go * (2.f / (1.f + __expf(-2.f * c)) - 1.f);
                h_all[t * 64 + u] = h;                 // f32 history for tail
                ((_Float16*)hwork)[u] = (_Float16)h;   // f16 row for next step
                // same-wave DS ops are in-order; compiler inserts lgkm waits
            }
        }
        __syncthreads();   // h_all + w1s visible to all 4 waves

        // ---- G tail (all 256 threads): G[b*100+row][j] = h(row) . W1[:,j] ----
        const int brow0 = b * TT;
        for (int idx = tid; idx < TT * 13; idx += 256) {
            int row = idx / 13;
            int m = idx - row * 13;
            int j = 4 * m;
            const float* hrow = &h_all[row * 64];
            float ax = 0.f, ay = 0.f, az = 0.f, aw = 0.f;
#pragma unroll
            for (int u4 = 0; u4 < 16; ++u4) {
                float4 hv  = *(const float4*)&hrow[4 * u4];
                float4 w0  = *(const float4*)&w1s[(4 * u4 + 0) * 52 + j];
                float4 w1v = *(const float4*)&w1s[(4 * u4 + 1) * 52 + j];
                float4 w2  = *(const float4*)&w1s[(4 * u4 + 2) * 52 + j];
                float4 w3  = *(const float4*)&w1s[(4 * u4 + 3) * 52 + j];
                ax += hv.x * w0.x + hv.y * w1v.x + hv.z * w2.x + hv.w * w3.x;
                ay += hv.x * w0.y + hv.y * w1v.y + hv.z * w2.y + hv.w * w3.y;
                az += hv.x * w0.z + hv.y * w1v.z + hv.z * w2.z + hv.w * w3.z;
                aw += hv.x * w0.w + hv.y * w1v.w + hv.z * w2.w + hv.w * w3.w;
            }
            if (m == 12) { az = 0.f; aw = 0.f; }   // cols 50,51 = 0
            *(float4*)&G[(brow0 + row) * GROW + j] = make_float4(ax, ay, az, aw);
        }
    } else {
        // ---- k3: XcT[j][p] = b1[j] + sum_k X[p][k]*W1[64+k][j] ----
        float* Xs  = smem;          // [128][65]
        float* W1T = smem + 8320;   // [50][128]
        const int p0 = (blockIdx.x - 8) * 64;
        for (int idx = tid; idx < 6400; idx += 256) {
            int k = idx & 127, jj = idx >> 7;
            W1T[jj * 128 + k] = W1[(64 + k) * 50 + jj];
        }
#pragma unroll
        for (int r = 0; r < 8; ++r) {
            int flat = (tid + 256 * r) * 4;
            int i = flat >> 7;
            int k = flat & 127;
            int p = p0 + i;
            float4 v = make_float4(0.f, 0.f, 0.f, 0.f);
            if (p < PP) v = *(const float4*)&X[p * 128 + k];
            Xs[(k + 0) * 65 + i] = v.x;
            Xs[(k + 1) * 65 + i] = v.y;
            Xs[(k + 2) * 65 + i] = v.z;
            Xs[(k + 3) * 65 + i] = v.w;
        }
        __syncthreads();
        const int ploc = tid & 63;
        const int j0 = tid >> 6;
        float acc[13];
#pragma unroll
        for (int m = 0; m < 13; ++m) {
            int jj = j0 * 13 + m;
            acc[m] = (jj < 50) ? b1[jj] : 0.f;
        }
        for (int k4 = 0; k4 < 32; ++k4) {
            const int k = 4 * k4;
            float x0 = Xs[(k + 0) * 65 + ploc];
            float x1 = Xs[(k + 1) * 65 + ploc];
            float x2 = Xs[(k + 2) * 65 + ploc];
            float x3 = Xs[(k + 3) * 65 + ploc];
#pragma unroll
            for (int m = 0; m < 13; ++m) {
                int jj = j0 * 13 + m;
                if (jj < 50) {
                    float4 wv = *(const float4*)&W1T[jj * 128 + k];
                    acc[m] += x0 * wv.x + x1 * wv.y + x2 * wv.z + x3 * wv.w;
                }
            }
        }
        int p = p0 + ploc;
        if (p < PP) {
#pragma unroll
            for (int m = 0; m < 13; ++m) {
                int jj = j0 * 13 + m;
                if (jj < 50) XcT[jj * PP + p] = acc[m];
            }
        }
        for (int idx = tid; idx < 6 * 64; idx += 256) {
            int r = 50 + (idx >> 6);
            int pp = p0 + (idx & 63);
            if (pp < PP) XcT[r * PP + pp] = 0.f;
        }
    }
}

// ---------------- K4: suffix-accumulate V[p,j] += a[s,p]*Gs[s,j]; emit per t-chunk -----
__global__ __launch_bounds__(256) void k4_main(const int* __restrict__ pro_id,
    const float* __restrict__ cos_X, const float* __restrict__ XcT,
    const float* __restrict__ G, const float* __restrict__ W2,
    const float* __restrict__ b2, float* __restrict__ out)
{
    __shared__ __align__(16) float Gs[TT * GROW];  // 22.4 KB
    __shared__ float w2s[NJ];
    __shared__ int spid[TT];
    const int b = blockIdx.z;
    const int p = blockIdx.y * 256 + threadIdx.x;
    const int ci = blockIdx.x;
    const int t0 = ci * 7;
    const int t1 = (t0 + 7 < TT) ? (t0 + 7) : TT;
    const bool valid = p < PP;
    const int pc = valid ? p : 0;
    const int tid = threadIdx.x;

    {
        const float4* Gg = (const float4*)(G + b * TT * GROW);
        float4* Gd = (float4*)Gs;
        for (int idx = tid; idx < TT * GROW / 4; idx += 256) Gd[idx] = Gg[idx];
        if (tid < TT) spid[tid] = pro_id[b * TT + tid];
        if (tid < NJ) w2s[tid] = (tid < 50) ? W2[tid] : 0.f;
    }

    float V[NJ];
#pragma unroll
    for (int jj = 0; jj < NJ; ++jj) V[jj] = XcT[jj * PP + pc];
    const float b2v = b2[0];
    __syncthreads();

    const float* cb = cos_X + pc;
    float a0 = cb[spid[99] * PP];
    float a1 = cb[spid[98] * PP];
    float a2 = cb[spid[97] * PP];
    float a3 = cb[spid[96] * PP];

    for (int s = TT - 1; s >= t0; --s) {
        float a = a0; a0 = a1; a1 = a2; a2 = a3;
        int sp = s - 4;
        if (sp < t0) sp = t0;
        a3 = cb[spid[sp] * PP];
        const float4* G4 = (const float4*)&Gs[s * GROW];
#pragma unroll
        for (int jv = 0; jv < 13; ++jv) {
            float4 gv = G4[jv];
            V[4 * jv + 0] += a * gv.x;
            V[4 * jv + 1] += a * gv.y;
            V[4 * jv + 2] += a * gv.z;
            V[4 * jv + 3] += a * gv.w;
        }
        if (s < t1) {
            float acc = b2v;
#pragma unroll
            for (int jv = 0; jv < 13; ++jv) {
                float4 wv = *(const float4*)&w2s[4 * jv];
                acc += wv.x * fmaxf(V[4 * jv + 0], 0.f)
                     + wv.y * fmaxf(V[4 * jv + 1], 0.f)
                     + wv.z * fmaxf(V[4 * jv + 2], 0.f)
                     + wv.w * fmaxf(V[4 * jv + 3], 0.f);
            }
            if (valid) out[(b * TT + s) * PP + p] = acc;
        }
    }
}

extern "C" void kernel_launch(void* const* d_in, const int* in_sizes, int n_in,
                              void* d_out, int out_size, void* d_ws, size_t ws_size,
                              hipStream_t stream)
{
    const int* pro_id  = (const int*)d_in[0];
    const int* label   = (const int*)d_in[1];
    const float* X     = (const float*)d_in[3];
    const float* cos_X = (const float*)d_in[4];
    // d_in[5] trimatrix: structurally tril(ones) — suffix-sum semantics hardcoded
    const float* onehot = (const float*)d_in[6];
    const float* lk    = (const float*)d_in[7];
    const float* lr    = (const float*)d_in[8];
    const float* lb    = (const float*)d_in[9];
    const float* W1    = (const float*)d_in[10];
    const float* b1    = (const float*)d_in[11];
    const float* W2    = (const float*)d_in[12];
    const float* b2    = (const float*)d_in[13];

    float* ws  = (float*)d_ws;
    float* xk  = ws;            // 204800
    float* XcT = ws + 204800;   // 56000
    float* G   = ws + 260800;   // 44800
    float* out = (float*)d_out;

    hipLaunchKernelGGL(k1_xk,  dim3(400),      dim3(256), 0, stream,
                       pro_id, label, X, onehot, lk, lb, xk);
    hipLaunchKernelGGL(mid,    dim3(24),       dim3(256), 0, stream,
                       xk, lr, W1, X, b1, G, XcT);
    hipLaunchKernelGGL(k4_main,dim3(15, 4, 8), dim3(256), 0, stream,
                       pro_id, cos_X, XcT, G, W2, b2, out);
}